// Round 6
// baseline (598.447 us; speedup 1.0000x reference)
//
#include <hip/hip_runtime.h>
#include <hip/hip_bf16.h>

// SR-GNN session model, MI355X (gfx950).
// Inputs fp32/int32 (probe-verified r3/r4); OUTPUT IS FP32 (r5 canary +
// out_npz_mb=758 proves fp32: bf16 would be <=410MB raw).
//
// ws layout: [0) s_g fp32 : 4096 x 32 f32  (512 KB)

#define B_BATCH 4096
#define N_NODE  16
#define L_SEQ   20
#define D_DIM   32
#define V_CAND  50000
#define NV_OUT  49999

typedef float f32x4 __attribute__((ext_vector_type(4)));

__device__ __forceinline__ float sigf(float x) {
    return 1.0f / (1.0f + __expf(-x));
}

// ---------------------------------------------------------------- kernel 1
// One block per session. All per-sample tensors live in LDS (fp32).
__global__ __launch_bounds__(256) void session_kernel(
    const int*   __restrict__ alias_inputs,  // [B,L]
    const float* __restrict__ A,             // [B,N,2N]
    const int*   __restrict__ items,         // [B,N]
    const int*   __restrict__ mask,          // [B,L]
    const float* __restrict__ emb,           // [V,D]
    const float* __restrict__ w_ih,          // [3D,2D]
    const float* __restrict__ w_hh,          // [3D,D]
    const float* __restrict__ b_ih, const float* __restrict__ b_hh,
    const float* __restrict__ b_iah, const float* __restrict__ b_oah,
    const float* __restrict__ w_ein, const float* __restrict__ b_ein,
    const float* __restrict__ w_eout, const float* __restrict__ b_eout,
    const float* __restrict__ w1, const float* __restrict__ b1,
    const float* __restrict__ w2, const float* __restrict__ b2,
    const float* __restrict__ w3,
    float* __restrict__ sg_out)              // [B,D] fp32 (ws)
{
    const int b   = blockIdx.x;
    const int tid = threadIdx.x;

    __shared__ float h_s [N_NODE][D_DIM];
    __shared__ float A_s [N_NODE][2 * N_NODE];
    __shared__ float ni_s[N_NODE][D_DIM];
    __shared__ float no_s[N_NODE][D_DIM];
    __shared__ float ii_s[N_NODE][D_DIM];
    __shared__ float io_s[N_NODE][D_DIM];
    __shared__ float gi_s[N_NODE][3 * D_DIM];
    __shared__ float gh_s[N_NODE][3 * D_DIM];
    __shared__ float seq_s[L_SEQ][D_DIM];
    __shared__ float q1_s[D_DIM];
    __shared__ float alpha_s[L_SEQ];
    __shared__ int   last_s;

    // P0: gather item embeddings, load adjacency
    for (int idx = tid; idx < N_NODE * D_DIM; idx += 256) {
        const int n = idx >> 5, d = idx & 31;
        const int it = items[b * N_NODE + n];
        h_s[n][d] = emb[(size_t)it * D_DIM + d];
        A_s[n][d] = A[(size_t)b * 512 + idx];
    }
    __syncthreads();

    // P1: node_in = h @ w_ein + b_ein ; node_out = h @ w_eout + b_eout
    for (int idx = tid; idx < N_NODE * D_DIM; idx += 256) {
        const int n = idx >> 5, d = idx & 31;
        float ai = b_ein[d], ao = b_eout[d];
        #pragma unroll
        for (int k = 0; k < D_DIM; ++k) {
            const float hv = h_s[n][k];
            ai += hv * w_ein[k * D_DIM + d];
            ao += hv * w_eout[k * D_DIM + d];
        }
        ni_s[n][d] = ai;
        no_s[n][d] = ao;
    }
    __syncthreads();

    // P2: input_in = A_in @ node_in + b_iah ; input_out = A_out @ node_out + b_oah
    for (int idx = tid; idx < N_NODE * D_DIM; idx += 256) {
        const int n = idx >> 5, d = idx & 31;
        float ii = b_iah[d], io = b_oah[d];
        #pragma unroll
        for (int m = 0; m < N_NODE; ++m) {
            ii += A_s[n][m]          * ni_s[m][d];
            io += A_s[n][N_NODE + m] * no_s[m][d];
        }
        ii_s[n][d] = ii;
        io_s[n][d] = io;
    }
    __syncthreads();

    // P3: gi = [input_in, input_out] @ w_ih^T + b_ih ; gh = h @ w_hh^T + b_hh
    for (int idx = tid; idx < N_NODE * 96; idx += 256) {
        const int n = idx / 96, j = idx % 96;
        float gi = b_ih[j], gh = b_hh[j];
        #pragma unroll
        for (int k = 0; k < D_DIM; ++k) {
            gi += ii_s[n][k] * w_ih[j * 64 + k];
            gi += io_s[n][k] * w_ih[j * 64 + 32 + k];
            gh += h_s[n][k]  * w_hh[j * 32 + k];
        }
        gi_s[n][j] = gi;
        gh_s[n][j] = gh;
    }
    __syncthreads();

    // P4: GRU cell, update h in place
    for (int idx = tid; idx < N_NODE * D_DIM; idx += 256) {
        const int n = idx >> 5, d = idx & 31;
        const float i_r = gi_s[n][d],      h_r = gh_s[n][d];
        const float i_i = gi_s[n][32 + d], h_i = gh_s[n][32 + d];
        const float i_n = gi_s[n][64 + d], h_n = gh_s[n][64 + d];
        const float rg = sigf(i_r + h_r);
        const float ig = sigf(i_i + h_i);
        const float x  = i_n + rg * h_n;
        const float ax = fabsf(x);
        const float e  = __expf(2.0f * ax);
        const float ng = copysignf(1.0f - 2.0f / (e + 1.0f), x);
        const float hv = h_s[n][d];
        h_s[n][d] = ng + ig * (hv - ng);
    }
    __syncthreads();

    // P5: seq gather + last index
    for (int idx = tid; idx < L_SEQ * D_DIM; idx += 256) {
        const int t = idx >> 5, d = idx & 31;
        const int a = alias_inputs[b * L_SEQ + t];
        seq_s[t][d] = h_s[a][d];
    }
    if (tid == 0) {
        int s = 0;
        for (int t = 0; t < L_SEQ; ++t) s += mask[b * L_SEQ + t];
        last_s = s - 1;
    }
    __syncthreads();

    // P6: q1 = ht @ w1 + b1
    if (tid < D_DIM) {
        const int d = tid;
        const int lt = last_s;
        float acc = b1[d];
        #pragma unroll
        for (int k = 0; k < D_DIM; ++k) acc += seq_s[lt][k] * w1[k * D_DIM + d];
        q1_s[d] = acc;
    }
    __syncthreads();

    // P7: alpha[t] = sum_d sigmoid(q1[d] + q2[t,d]) * w3[d]
    float* tmp = &gi_s[0][0];
    for (int idx = tid; idx < L_SEQ * D_DIM; idx += 256) {
        const int t = idx >> 5, d = idx & 31;
        float q2 = b2[d];
        #pragma unroll
        for (int k = 0; k < D_DIM; ++k) q2 += seq_s[t][k] * w2[k * D_DIM + d];
        tmp[idx] = sigf(q1_s[d] + q2) * w3[d];
    }
    __syncthreads();
    if (tid < L_SEQ) {
        float a = 0.0f;
        #pragma unroll
        for (int d = 0; d < D_DIM; ++d) a += tmp[tid * D_DIM + d];
        alpha_s[tid] = a * (float)mask[b * L_SEQ + tid];
    }
    __syncthreads();

    // P8: s_g[d] = sum_t alpha[t] * seq[t,d]
    if (tid < D_DIM) {
        const int d = tid;
        float acc = 0.0f;
        #pragma unroll
        for (int t = 0; t < L_SEQ; ++t) acc += alpha_s[t] * seq_s[t][d];
        sg_out[b * D_DIM + d] = acc;
    }
}

// ---------------------------------------------------------------- kernel 2
// scores[b, v] = sum_d s_g[b,d] * emb[1+v, d]  — fp32 VALU, FP32 OUTPUT.
// Block: 256 threads = 256 v-columns, 16 b-rows (sg tile in LDS).
// Grid: (ceil(49999/256) = 196, 4096/16 = 256).  Write-BW-bound (~819 MB).
__global__ __launch_bounds__(256) void score_fp32_kernel(
    const float* __restrict__ sg,    // [4096, 32] f32 (ws)
    const float* __restrict__ emb,   // [50000, 32] f32
    float* __restrict__ out)         // [4096, 49999] f32
{
    __shared__ float sg_s[16][32];
    const int tid = threadIdx.x;
    const int b0  = blockIdx.y * 16;
    const int v   = blockIdx.x * 256 + tid;

    if (tid < 128) {
        reinterpret_cast<f32x4*>(&sg_s[0][0])[tid] =
            reinterpret_cast<const f32x4*>(&sg[(size_t)b0 * D_DIM])[tid];
    }
    __syncthreads();
    if (v >= NV_OUT) return;

    f32x4 er[8];
    const f32x4* ep = reinterpret_cast<const f32x4*>(&emb[(size_t)(1 + v) * D_DIM]);
    #pragma unroll
    for (int i = 0; i < 8; ++i) er[i] = ep[i];

    #pragma unroll
    for (int r = 0; r < 16; ++r) {
        const float* s = sg_s[r];
        float acc = 0.0f;
        #pragma unroll
        for (int i = 0; i < 8; ++i) {
            acc += er[i][0] * s[4 * i + 0];
            acc += er[i][1] * s[4 * i + 1];
            acc += er[i][2] * s[4 * i + 2];
            acc += er[i][3] * s[4 * i + 3];
        }
        out[(size_t)(b0 + r) * NV_OUT + v] = acc;
    }
}

// ---------------------------------------------------------------- launch
extern "C" void kernel_launch(void* const* d_in, const int* in_sizes, int n_in,
                              void* d_out, int out_size, void* d_ws, size_t ws_size,
                              hipStream_t stream)
{
    const int*   alias_inputs = (const int*)  d_in[0];
    const float* A      = (const float*)d_in[1];
    const int*   items  = (const int*)  d_in[2];
    const int*   mask   = (const int*)  d_in[3];
    const float* emb    = (const float*)d_in[4];
    const float* w_ih   = (const float*)d_in[5];
    const float* w_hh   = (const float*)d_in[6];
    const float* b_ih   = (const float*)d_in[7];
    const float* b_hh   = (const float*)d_in[8];
    const float* b_iah  = (const float*)d_in[9];
    const float* b_oah  = (const float*)d_in[10];
    const float* w_ein  = (const float*)d_in[11];
    const float* b_ein  = (const float*)d_in[12];
    const float* w_eout = (const float*)d_in[13];
    const float* b_eout = (const float*)d_in[14];
    const float* w1     = (const float*)d_in[15];
    const float* b1     = (const float*)d_in[16];
    const float* w2     = (const float*)d_in[17];
    const float* b2     = (const float*)d_in[18];
    const float* w3     = (const float*)d_in[19];

    float* sg  = (float*)d_ws;                     // 4096*32 f32
    float* out = (float*)d_out;                    // FP32 output

    hipLaunchKernelGGL(session_kernel, dim3(B_BATCH), dim3(256), 0, stream,
                       alias_inputs, A, items, mask, emb,
                       w_ih, w_hh, b_ih, b_hh, b_iah, b_oah,
                       w_ein, b_ein, w_eout, b_eout,
                       w1, b1, w2, b2, w3, sg);

    const int ntv = (NV_OUT + 255) / 256;   // 196
    hipLaunchKernelGGL(score_fp32_kernel, dim3(ntv, B_BATCH / 16), dim3(256), 0, stream,
                       sg, emb, out);
}